// Round 1
// baseline (414.494 us; speedup 1.0000x reference)
//
#include <hip/hip_runtime.h>
#include <hip/hip_bf16.h>
#include <math.h>

#define N_TOK 8192
#define D_MODEL 512
#define N_EXP 8

// ---- workspace layout (bytes) ----
// 0      : int   count[8]
// 64     : float imp[8]
// 256    : float tok_g[2*N_TOK]            (64 KB)
// 65792  : int   bucket[N_EXP*N_TOK]       (256 KB)
// 1 MB   : float y[2*N_TOK*D_MODEL]        (32 MB)  per-slot expert outputs

__global__ __launch_bounds__(256) void gate_kernel(
    const float* __restrict__ x, const float* __restrict__ wg,
    int* __restrict__ count, float* __restrict__ imp,
    float* __restrict__ tok_g, int* __restrict__ bucket)
{
    __shared__ float wgs[N_EXP * D_MODEL];   // transposed [e][d] -> conflict-free
    __shared__ float imp_s[N_EXP];
    for (int i = threadIdx.x; i < N_EXP * D_MODEL; i += 256) {
        int d = i >> 3, e = i & 7;           // w_gate flat = d*8+e
        wgs[e * D_MODEL + d] = wg[i];
    }
    if (threadIdx.x < N_EXP) imp_s[threadIdx.x] = 0.f;
    __syncthreads();

    int wave = threadIdx.x >> 6, lane = threadIdx.x & 63;
    int n = blockIdx.x * 4 + wave;
    const float* xr = x + (size_t)n * D_MODEL;

    float p[N_EXP];
#pragma unroll
    for (int e = 0; e < N_EXP; ++e) p[e] = 0.f;
#pragma unroll
    for (int it = 0; it < 8; ++it) {
        float xv = xr[it * 64 + lane];
#pragma unroll
        for (int e = 0; e < N_EXP; ++e)
            p[e] += xv * wgs[e * D_MODEL + it * 64 + lane];
    }
#pragma unroll
    for (int off = 32; off > 0; off >>= 1) {
#pragma unroll
        for (int e = 0; e < N_EXP; ++e)
            p[e] += __shfl_xor(p[e], off);
    }

    if (lane == 0) {
        // top-2, ties -> lowest index (jax.lax.top_k semantics)
        int e1 = 0; float v1 = p[0];
#pragma unroll
        for (int e = 1; e < N_EXP; ++e) if (p[e] > v1) { v1 = p[e]; e1 = e; }
        int e2 = -1; float v2 = -INFINITY;
#pragma unroll
        for (int e = 0; e < N_EXP; ++e) if (e != e1 && p[e] > v2) { v2 = p[e]; e2 = e; }
        float t = __expf(v2 - v1);
        float inv = 1.f / (1.f + t);
        float g1 = inv, g2 = t * inv;
        tok_g[2 * n]     = g1;
        tok_g[2 * n + 1] = g2;
        int p1 = atomicAdd(&count[e1], 1); bucket[e1 * N_TOK + p1] = 2 * n;
        int p2 = atomicAdd(&count[e2], 1); bucket[e2 * N_TOK + p2] = 2 * n + 1;
        atomicAdd(&imp_s[e1], g1);
        atomicAdd(&imp_s[e2], g2);
    }
    __syncthreads();
    if (threadIdx.x < N_EXP) atomicAdd(&imp[threadIdx.x], imp_s[threadIdx.x]);
}

// grouped GEMM: y[slot][f] = x[slot>>1] dot W[e][:, f] over the expert's bucket
__global__ __launch_bounds__(256) void moe_gemm(
    const float* __restrict__ x, const float* __restrict__ ew,
    const int* __restrict__ count, const int* __restrict__ bucket,
    float* __restrict__ y)
{
    int ft = blockIdx.x & 7;        // feature tile (64 cols)
    int eb = blockIdx.x >> 3;
    int e  = eb >> 7;               // expert
    int tt = eb & 127;              // token tile (64 slots)
    int cnt = count[e];
    int t0 = tt * 64;
    if (t0 >= cnt) return;

    __shared__ int sl[64];
    __shared__ __align__(16) float As[64][33];   // [row][k], +1 pad
    __shared__ __align__(16) float Bs[32][68];   // [k][col], stride keeps 16B align

    int tid = threadIdx.x;
    if (tid < 64) {
        int idx = t0 + tid;
        sl[tid] = (idx < cnt) ? bucket[e * N_TOK + idx] : -1;
    }
    __syncthreads();

    // A-load mapping: 4 threads per row, 8 floats each
    int ar = tid >> 2;
    int ac = (tid & 3) * 8;
    int slot_a = sl[ar];
    const float* aptr = (slot_a >= 0)
        ? x + (size_t)(slot_a >> 1) * D_MODEL + ac : nullptr;

    // B-load mapping: 8 threads per k-row, 8 floats each
    int br = tid >> 3;
    int bc = (tid & 7) * 8;
    const float* bptr = ew + ((size_t)e * D_MODEL + br) * D_MODEL + ft * 64 + bc;

    int ty = tid >> 4, tx = tid & 15;     // 16x16 thread grid, 4x4 micro-tile
    float acc[4][4];
#pragma unroll
    for (int i = 0; i < 4; ++i)
#pragma unroll
        for (int j = 0; j < 4; ++j) acc[i][j] = 0.f;

    for (int kc = 0; kc < 16; ++kc) {
        float4 a0 = {0,0,0,0}, a1 = {0,0,0,0};
        if (aptr) {
            const float* s = aptr + kc * 32;
            a0 = *(const float4*)(s);
            a1 = *(const float4*)(s + 4);
        }
        const float* bsrc = bptr + (size_t)kc * 32 * D_MODEL;
        float4 b0 = *(const float4*)(bsrc);
        float4 b1 = *(const float4*)(bsrc + 4);

        __syncthreads();   // protect previous iteration's LDS reads
        As[ar][ac + 0] = a0.x; As[ar][ac + 1] = a0.y;
        As[ar][ac + 2] = a0.z; As[ar][ac + 3] = a0.w;
        As[ar][ac + 4] = a1.x; As[ar][ac + 5] = a1.y;
        As[ar][ac + 6] = a1.z; As[ar][ac + 7] = a1.w;
        *(float4*)&Bs[br][bc]     = b0;
        *(float4*)&Bs[br][bc + 4] = b1;
        __syncthreads();

#pragma unroll
        for (int k = 0; k < 32; ++k) {
            float av[4];
#pragma unroll
            for (int i = 0; i < 4; ++i) av[i] = As[ty * 4 + i][k];
            float4 bv = *(const float4*)&Bs[k][tx * 4];
#pragma unroll
            for (int i = 0; i < 4; ++i) {
                acc[i][0] += av[i] * bv.x;
                acc[i][1] += av[i] * bv.y;
                acc[i][2] += av[i] * bv.z;
                acc[i][3] += av[i] * bv.w;
            }
        }
    }

    int fbase = ft * 64 + tx * 4;
#pragma unroll
    for (int i = 0; i < 4; ++i) {
        int r = ty * 4 + i;
        int s = sl[r];
        if (s >= 0) {
            float4 v = { acc[i][0], acc[i][1], acc[i][2], acc[i][3] };
            *(float4*)(y + (size_t)s * D_MODEL + fbase) = v;
        }
    }
}

__global__ __launch_bounds__(256) void combine_kernel(
    const float* __restrict__ y, const float* __restrict__ tok_g,
    float* __restrict__ out)
{
    int idx = blockIdx.x * 256 + threadIdx.x;  // float4 index, 0..(N*D/4-1)
    int n = idx >> 7;                          // 128 float4 per token row
    int c = idx & 127;
    const float4* y4 = (const float4*)y;
    float4 a = y4[(size_t)n * 256 + c];        // slot 2n
    float4 b = y4[(size_t)n * 256 + 128 + c];  // slot 2n+1
    float g1 = tok_g[2 * n], g2 = tok_g[2 * n + 1];
    const float eps = 2.2204460492503131e-16f; // float32(finfo(float64).eps)
    float4 r;
    float v;
    v = g1 * expf(a.x) + g2 * expf(b.x); r.x = logf(v == 0.f ? eps : v);
    v = g1 * expf(a.y) + g2 * expf(b.y); r.y = logf(v == 0.f ? eps : v);
    v = g1 * expf(a.z) + g2 * expf(b.z); r.z = logf(v == 0.f ? eps : v);
    v = g1 * expf(a.w) + g2 * expf(b.w); r.w = logf(v == 0.f ? eps : v);
    ((float4*)out)[idx] = r;
}

__global__ void loss_kernel(const int* __restrict__ count,
                            const float* __restrict__ imp,
                            float* __restrict__ out)
{
    if (threadIdx.x == 0 && blockIdx.x == 0) {
        float mi = 0.f, ml = 0.f;
        for (int e = 0; e < N_EXP; ++e) { mi += imp[e]; ml += (float)count[e]; }
        mi *= 0.125f; ml *= 0.125f;
        float vi = 0.f, vl = 0.f;
        for (int e = 0; e < N_EXP; ++e) {
            float di = imp[e] - mi;          vi += di * di;
            float dl = (float)count[e] - ml; vl += dl * dl;
        }
        vi *= 0.125f; vl *= 0.125f;
        out[N_TOK * D_MODEL] = vi / (mi * mi + 1e-10f) + vl / (ml * ml + 1e-10f);
    }
}

extern "C" void kernel_launch(void* const* d_in, const int* in_sizes, int n_in,
                              void* d_out, int out_size, void* d_ws, size_t ws_size,
                              hipStream_t stream)
{
    const float* x  = (const float*)d_in[0];
    const float* wg = (const float*)d_in[1];
    const float* ew = (const float*)d_in[2];
    char* ws = (char*)d_ws;
    int*   count  = (int*)(ws + 0);
    float* imp    = (float*)(ws + 64);
    float* tok_g  = (float*)(ws + 256);
    int*   bucket = (int*)(ws + 65792);
    float* y      = (float*)(ws + (1u << 20));
    float* out    = (float*)d_out;

    hipMemsetAsync(ws, 0, 128, stream);                                  // counts+imp
    gate_kernel<<<N_TOK / 4, 256, 0, stream>>>(x, wg, count, imp, tok_g, bucket);
    moe_gemm<<<N_EXP * 128 * 8, 256, 0, stream>>>(x, ew, count, bucket, y);
    combine_kernel<<<(N_TOK * D_MODEL / 4) / 256, 256, 0, stream>>>(y, tok_g, out);
    loss_kernel<<<1, 64, 0, stream>>>(count, imp, out);
}

// Round 2
// 122.213 us; speedup vs baseline: 3.3916x; 3.3916x over previous
//
#include <hip/hip_runtime.h>
#include <hip/hip_bf16.h>
#include <math.h>

#define N_TOK 8192
#define D 512
#define NE 8

typedef float f32x4 __attribute__((ext_vector_type(4)));
typedef __bf16 bf16x8 __attribute__((ext_vector_type(8)));
typedef unsigned short u16;

// ---- workspace layout (bytes) ----
// 0        int   count[8]
// 64       float imp[8]
// 256      int   tok_e[2*N_TOK]    (64 KB)  expert ids per slot
// 65792    float tok_g[2*N_TOK]    (64 KB)  gate weights per slot
// 131328   int   bucket[NE*N_TOK]  (256 KB)
// 1 MB     u16   xb[N_TOK*D]       (8 MB)   x in bf16
// 9 MB+    u16   ewt[NE*D*D]       (4 MB)   expert_w transposed [e][f][d] bf16
// 13 MB+   u16   y[2*N_TOK*D]      (16 MB)  per-slot expert outputs bf16
#define OFF_TOKE  256
#define OFF_TOKG  65792
#define OFF_BUCK  131328
#define OFF_XB    (1u << 20)
#define OFF_EWT   (OFF_XB + 8u * 1024 * 1024)
#define OFF_Y     (OFF_EWT + 4u * 1024 * 1024)

__device__ __forceinline__ u16 f2b(float v) {
    __hip_bfloat16 h = __float2bfloat16(v);
    return *reinterpret_cast<u16*>(&h);
}
__device__ __forceinline__ float b2f(u16 u) {
    __hip_bfloat16 h;
    *reinterpret_cast<u16*>(&h) = u;
    return __bfloat162float(h);
}

typedef __attribute__((address_space(1))) const void* gp1_t;
typedef __attribute__((address_space(3))) void* lp3_t;
__device__ __forceinline__ void gload16(const void* g, void* l) {
    __builtin_amdgcn_global_load_lds((gp1_t)g, (lp3_t)l, 16, 0, 0);
}

// -------- gate: logits -> top2 -> softmax; also convert x to bf16. NO atomics.
__global__ __launch_bounds__(256) void gate_kernel(
    const float* __restrict__ x, const float* __restrict__ wg,
    int* __restrict__ tok_e, float* __restrict__ tok_g, u16* __restrict__ xb)
{
    __shared__ float wgs[NE * D];   // [e][d] transposed, conflict-free reads
    for (int i = threadIdx.x; i < NE * D; i += 256) {
        int d = i >> 3, e = i & 7;  // w_gate flat = d*8 + e
        wgs[e * D + d] = wg[i];
    }
    __syncthreads();

    int wave = threadIdx.x >> 6, lane = threadIdx.x & 63;
    int n = blockIdx.x * 4 + wave;
    const float* xr = x + (size_t)n * D;
    u16* xbr = xb + (size_t)n * D;

    float p[NE];
#pragma unroll
    for (int e = 0; e < NE; ++e) p[e] = 0.f;
#pragma unroll
    for (int it = 0; it < 8; ++it) {
        float xv = xr[it * 64 + lane];
        xbr[it * 64 + lane] = f2b(xv);
#pragma unroll
        for (int e = 0; e < NE; ++e)
            p[e] += xv * wgs[e * D + it * 64 + lane];
    }
#pragma unroll
    for (int off = 32; off > 0; off >>= 1) {
#pragma unroll
        for (int e = 0; e < NE; ++e)
            p[e] += __shfl_xor(p[e], off);
    }

    if (lane == 0) {
        // top-2, ties -> lowest index (jax.lax.top_k semantics)
        int e1 = 0; float v1 = p[0];
#pragma unroll
        for (int e = 1; e < NE; ++e) if (p[e] > v1) { v1 = p[e]; e1 = e; }
        int e2 = -1; float v2 = -INFINITY;
#pragma unroll
        for (int e = 0; e < NE; ++e) if (e != e1 && p[e] > v2) { v2 = p[e]; e2 = e; }
        float t = __expf(v2 - v1);
        float inv = 1.f / (1.f + t);
        tok_e[2 * n] = e1;     tok_e[2 * n + 1] = e2;
        tok_g[2 * n] = inv;    tok_g[2 * n + 1] = t * inv;
    }
}

// -------- bucketize: two-level offsets, 512 global atomics total
__global__ __launch_bounds__(256) void bucketize_kernel(
    const int* __restrict__ tok_e, const float* __restrict__ tok_g,
    int* __restrict__ count, float* __restrict__ imp, int* __restrict__ bucket)
{
    __shared__ int lcnt[NE], lbase[NE];
    __shared__ float limp[NE];
    int tid = threadIdx.x;
    if (tid < NE) { lcnt[tid] = 0; limp[tid] = 0.f; }
    __syncthreads();

    int n = blockIdx.x * 256 + tid;          // one token per thread, 32 blocks
    int e1 = tok_e[2 * n], e2 = tok_e[2 * n + 1];
    float g1 = tok_g[2 * n], g2 = tok_g[2 * n + 1];
    int o1 = atomicAdd(&lcnt[e1], 1);
    int o2 = atomicAdd(&lcnt[e2], 1);
    atomicAdd(&limp[e1], g1);
    atomicAdd(&limp[e2], g2);
    __syncthreads();
    if (tid < NE) {
        lbase[tid] = atomicAdd(&count[tid], lcnt[tid]);
        atomicAdd(&imp[tid], limp[tid]);
    }
    __syncthreads();
    bucket[e1 * N_TOK + lbase[e1] + o1] = 2 * n;
    bucket[e2 * N_TOK + lbase[e2] + o2] = 2 * n + 1;
}

// -------- transpose-convert expert_w [e][d][f] fp32 -> ewt [e][f][d] bf16
__global__ __launch_bounds__(256) void prep_w_kernel(
    const float* __restrict__ ew, u16* __restrict__ ewt)
{
    __shared__ float tile[64][65];
    int b = blockIdx.x;
    int e = b >> 6, dt = (b >> 3) & 7, ftl = b & 7;
    int t = threadIdx.x;
    int c = t & 63, rq = t >> 6;
    const float* src = ew + (size_t)e * D * D + (size_t)(dt * 64) * D + ftl * 64;
#pragma unroll
    for (int i = 0; i < 16; ++i) {
        int r = i * 4 + rq;
        tile[r][c] = src[(size_t)r * D + c];
    }
    __syncthreads();
    u16* dst = ewt + (size_t)e * D * D + (size_t)(ftl * 64) * D + dt * 64;
#pragma unroll
    for (int i = 0; i < 16; ++i) {
        int f = i * 4 + rq;
        dst[(size_t)f * D + c] = f2b(tile[c][f]);   // stride-65 read: conflict-free
    }
}

// -------- grouped GEMM, bf16 MFMA 16x16x32, 128x128 tile, BK=32 (m97 structure)
__global__ __launch_bounds__(256) void moe_gemm(
    const u16* __restrict__ xb, const u16* __restrict__ ewt,
    const int* __restrict__ count, const int* __restrict__ bucket,
    u16* __restrict__ y)
{
    int b = blockIdx.x;
    int ft = b & 3;            // feature tile (128 cols)
    int tt = (b >> 2) & 63;    // token tile (128 slots)
    int e  = b >> 8;           // expert
    int cnt = count[e];
    if (tt * 128 >= cnt) return;

    __shared__ int sl[128];
    __shared__ __align__(16) u16 As[128 * 32];   // [row][k] bf16, NO pad (gload)
    __shared__ __align__(16) u16 Bs[128 * 32];   // [f][k]   bf16

    int tid = threadIdx.x;
    if (tid < 128) {
        int idx = tt * 128 + tid;
        sl[tid] = (idx < cnt) ? bucket[e * N_TOK + idx] : -1;
    }
    __syncthreads();

    int w = tid >> 6, l = tid & 63;
    int c8 = (l & 3) * 8;
    int r0 = w * 32 + (l >> 2);     // staging rows: r0, r0+16
    int r1 = r0 + 16;
    int s0 = sl[r0], s1 = sl[r1];
    int ta0 = (s0 < 0) ? 0 : (s0 >> 1);
    int ta1 = (s1 < 0) ? 0 : (s1 >> 1);
    const u16* gA0 = xb + (size_t)ta0 * D + c8;
    const u16* gA1 = xb + (size_t)ta1 * D + c8;
    const u16* gB0 = ewt + ((size_t)e * D + ft * 128 + r0) * D + c8;
    const u16* gB1 = ewt + ((size_t)e * D + ft * 128 + r1) * D + c8;
    u16* lA0 = &As[(w * 32) * 32];
    u16* lA1 = &As[(w * 32 + 16) * 32];
    u16* lB0 = &Bs[(w * 32) * 32];
    u16* lB1 = &Bs[(w * 32 + 16) * 32];

    int wm = w & 1, wn = w >> 1;    // 2x2 waves, each 64x64 out
    int lm = l & 15, kq = (l >> 4) * 8;

    f32x4 acc[4][4] = {};

    for (int kc = 0; kc < 16; ++kc) {
        __syncthreads();                       // previous LDS reads done
        gload16(gA0 + kc * 32, lA0);
        gload16(gA1 + kc * 32, lA1);
        gload16(gB0 + kc * 32, lB0);
        gload16(gB1 + kc * 32, lB1);
        __syncthreads();                       // drains vmcnt -> LDS valid

        bf16x8 af[4], bfv[4];
#pragma unroll
        for (int i = 0; i < 4; ++i)
            af[i] = *(const bf16x8*)&As[(wm * 64 + i * 16 + lm) * 32 + kq];
#pragma unroll
        for (int j = 0; j < 4; ++j)
            bfv[j] = *(const bf16x8*)&Bs[(wn * 64 + j * 16 + lm) * 32 + kq];
#pragma unroll
        for (int i = 0; i < 4; ++i)
#pragma unroll
            for (int j = 0; j < 4; ++j)
                acc[i][j] = __builtin_amdgcn_mfma_f32_16x16x32_bf16(
                    af[i], bfv[j], acc[i][j], 0, 0, 0);
    }

    // C/D layout (m89-verified): col = lane&15, row = (lane>>4)*4 + reg
    int quad = l >> 4;
#pragma unroll
    for (int i = 0; i < 4; ++i) {
        int mbase = wm * 64 + i * 16 + quad * 4;
#pragma unroll
        for (int r = 0; r < 4; ++r) {
            int s = sl[mbase + r];
            if (s < 0) continue;
            u16* dst = y + (size_t)s * D + ft * 128 + wn * 64 + lm;
#pragma unroll
            for (int j = 0; j < 4; ++j)
                dst[j * 16] = f2b(acc[i][j][r]);
        }
    }
}

// -------- combine: out = log(g1*exp(y1) + g2*exp(y2))
__global__ __launch_bounds__(256) void combine_kernel(
    const u16* __restrict__ y, const float* __restrict__ tok_g,
    float* __restrict__ out)
{
    int idx = blockIdx.x * 256 + threadIdx.x;   // 4-elem group id
    int n = idx >> 7;                           // 128 groups per token
    int c = (idx & 127) * 4;
    const ushort4 ua = *(const ushort4*)(y + (size_t)(2 * n) * D + c);
    const ushort4 ub = *(const ushort4*)(y + (size_t)(2 * n + 1) * D + c);
    float g1 = tok_g[2 * n], g2 = tok_g[2 * n + 1];
    const float eps = 2.2204460492503131e-16f;
    float4 r;
    float v;
    v = g1 * __expf(b2f(ua.x)) + g2 * __expf(b2f(ub.x)); r.x = __logf(v == 0.f ? eps : v);
    v = g1 * __expf(b2f(ua.y)) + g2 * __expf(b2f(ub.y)); r.y = __logf(v == 0.f ? eps : v);
    v = g1 * __expf(b2f(ua.z)) + g2 * __expf(b2f(ub.z)); r.z = __logf(v == 0.f ? eps : v);
    v = g1 * __expf(b2f(ua.w)) + g2 * __expf(b2f(ub.w)); r.w = __logf(v == 0.f ? eps : v);
    *(float4*)(out + (size_t)n * D + c) = r;
}

__global__ void loss_kernel(const int* __restrict__ count,
                            const float* __restrict__ imp,
                            float* __restrict__ out)
{
    if (threadIdx.x == 0 && blockIdx.x == 0) {
        float mi = 0.f, ml = 0.f;
        for (int e = 0; e < NE; ++e) { mi += imp[e]; ml += (float)count[e]; }
        mi *= 0.125f; ml *= 0.125f;
        float vi = 0.f, vl = 0.f;
        for (int e = 0; e < NE; ++e) {
            float di = imp[e] - mi;          vi += di * di;
            float dl = (float)count[e] - ml; vl += dl * dl;
        }
        vi *= 0.125f; vl *= 0.125f;
        out[N_TOK * D] = vi / (mi * mi + 1e-10f) + vl / (ml * ml + 1e-10f);
    }
}

extern "C" void kernel_launch(void* const* d_in, const int* in_sizes, int n_in,
                              void* d_out, int out_size, void* d_ws, size_t ws_size,
                              hipStream_t stream)
{
    const float* x  = (const float*)d_in[0];
    const float* wg = (const float*)d_in[1];
    const float* ew = (const float*)d_in[2];
    char* ws = (char*)d_ws;
    int*   count  = (int*)(ws + 0);
    float* imp    = (float*)(ws + 64);
    int*   tok_e  = (int*)(ws + OFF_TOKE);
    float* tok_g  = (float*)(ws + OFF_TOKG);
    int*   bucket = (int*)(ws + OFF_BUCK);
    u16*   xb     = (u16*)(ws + OFF_XB);
    u16*   ewt    = (u16*)(ws + OFF_EWT);
    u16*   y      = (u16*)(ws + OFF_Y);
    float* out    = (float*)d_out;

    hipMemsetAsync(ws, 0, 128, stream);   // count + imp
    gate_kernel<<<N_TOK / 4, 256, 0, stream>>>(x, wg, tok_e, tok_g, xb);
    prep_w_kernel<<<NE * 64, 256, 0, stream>>>(ew, ewt);
    bucketize_kernel<<<N_TOK / 256, 256, 0, stream>>>(tok_e, tok_g, count, imp, bucket);
    moe_gemm<<<NE * 64 * 4, 256, 0, stream>>>(xb, ewt, count, bucket, y);
    combine_kernel<<<(N_TOK * D / 4) / 256, 256, 0, stream>>>(y, tok_g, out);
    loss_kernel<<<1, 64, 0, stream>>>(count, imp, out);
}

// Round 4
// 120.380 us; speedup vs baseline: 3.4432x; 1.0152x over previous
//
#include <hip/hip_runtime.h>
#include <hip/hip_bf16.h>
#include <math.h>

#define N_TOK 8192
#define D 512
#define NE 8

typedef float f32x4 __attribute__((ext_vector_type(4)));
typedef __bf16 bf16x8 __attribute__((ext_vector_type(8)));
typedef unsigned short u16;
typedef u16 u16x8 __attribute__((ext_vector_type(8)));

// ---- workspace layout (bytes) ----
// 0        int   count[8]
// 64       float imp[8]
// 256      int   tok_e[2*N_TOK]    (64 KB)
// 65792    float tok_g[2*N_TOK]    (64 KB)
// 131328   int   bucket[NE*N_TOK]  (256 KB)
// 1 MB     u16   xb[N_TOK*D]       (8 MB)   x in bf16
// 9 MB     u16   ewt[NE*D*D]       (4 MB)   expert_w [e][f][d] bf16
// 13 MB    u16   y[2*N_TOK*D]      (16 MB)  per-slot expert outputs bf16
#define OFF_TOKE  256
#define OFF_TOKG  65792
#define OFF_BUCK  131328
#define OFF_XB    (1u << 20)
#define OFF_EWT   (OFF_XB + 8u * 1024 * 1024)
#define OFF_Y     (OFF_EWT + 4u * 1024 * 1024)

__device__ __forceinline__ u16 f2b(float v) {
    __hip_bfloat16 h = __float2bfloat16(v);
    return *reinterpret_cast<u16*>(&h);
}
__device__ __forceinline__ float b2f(u16 u) {
    __hip_bfloat16 h;
    *reinterpret_cast<u16*>(&h) = u;
    return __bfloat162float(h);
}

typedef __attribute__((address_space(1))) const void* gp1_t;
typedef __attribute__((address_space(3))) void* lp3_t;
__device__ __forceinline__ void gload16(const void* g, void* l) {
    __builtin_amdgcn_global_load_lds((gp1_t)g, (lp3_t)l, 16, 0, 0);
}

// -------- fused: gate (blocks 0..2047) | prep_w transpose (blocks 2048..2559)
// NOTE: no count/imp zero-init here — that is done by hipMemsetAsync (round-3
// post-mortem: kernel-store zeroing consumed by next-kernel atomics diverged
// on graph replay; memset zeroing is the replay-proven path).
__global__ __launch_bounds__(256) void gate_prep_kernel(
    const float* __restrict__ x, const float* __restrict__ wg,
    const float* __restrict__ ew,
    int* __restrict__ tok_e, float* __restrict__ tok_g, u16* __restrict__ xb,
    u16* __restrict__ ewt)
{
    __shared__ __align__(16) float sbuf[64 * 65];   // 16.6 KB, both paths
    int b = blockIdx.x;
    int tid = threadIdx.x;

    if (b >= 2048) {
        // ---- prep path: expert_w [e][d][f] fp32 -> ewt [e][f][d] bf16
        int pb = b - 2048;
        float (*tile)[65] = (float(*)[65])sbuf;
        int e = pb >> 6, dt = (pb >> 3) & 7, ftl = pb & 7;
        int c = tid & 63, rq = tid >> 6;
        const float* src = ew + (size_t)e * D * D + (size_t)(dt * 64) * D + ftl * 64;
#pragma unroll
        for (int i = 0; i < 16; ++i) {
            int r = i * 4 + rq;
            tile[r][c] = src[(size_t)r * D + c];
        }
        __syncthreads();
        u16* dst = ewt + (size_t)e * D * D + (size_t)(ftl * 64) * D + dt * 64;
#pragma unroll
        for (int i = 0; i < 16; ++i) {
            int f = i * 4 + rq;
            dst[(size_t)f * D + c] = f2b(tile[c][f]);
        }
        return;
    }

    // ---- gate path
    float* wgs = sbuf;   // [e][d] transposed, conflict-free
    for (int i = tid; i < NE * D; i += 256) {
        int d = i >> 3, e = i & 7;   // w_gate flat = d*8 + e
        wgs[e * D + d] = wg[i];
    }
    __syncthreads();

    int wave = tid >> 6, lane = tid & 63;
    int n = b * 4 + wave;
    const float* xr = x + (size_t)n * D;
    u16* xbr = xb + (size_t)n * D;

    float p[NE];
#pragma unroll
    for (int e = 0; e < NE; ++e) p[e] = 0.f;
#pragma unroll
    for (int it = 0; it < 8; ++it) {
        float xv = xr[it * 64 + lane];
        xbr[it * 64 + lane] = f2b(xv);
#pragma unroll
        for (int e = 0; e < NE; ++e)
            p[e] += xv * wgs[e * D + it * 64 + lane];
    }
#pragma unroll
    for (int off = 32; off > 0; off >>= 1) {
#pragma unroll
        for (int e = 0; e < NE; ++e)
            p[e] += __shfl_xor(p[e], off);
    }

    if (lane == 0) {
        // top-2, ties -> lowest index (jax.lax.top_k semantics)
        int e1 = 0; float v1 = p[0];
#pragma unroll
        for (int e = 1; e < NE; ++e) if (p[e] > v1) { v1 = p[e]; e1 = e; }
        int e2 = -1; float v2 = -INFINITY;
#pragma unroll
        for (int e = 0; e < NE; ++e) if (e != e1 && p[e] > v2) { v2 = p[e]; e2 = e; }
        float t = __expf(v2 - v1);
        float inv = 1.f / (1.f + t);
        tok_e[2 * n] = e1;     tok_e[2 * n + 1] = e2;
        tok_g[2 * n] = inv;    tok_g[2 * n + 1] = t * inv;
    }
}

// -------- bucketize: two-level offsets, 512 global atomics (round-2 proven)
__global__ __launch_bounds__(256) void bucketize_kernel(
    const int* __restrict__ tok_e, const float* __restrict__ tok_g,
    int* __restrict__ count, float* __restrict__ imp, int* __restrict__ bucket)
{
    __shared__ int lcnt[NE], lbase[NE];
    __shared__ float limp[NE];
    int tid = threadIdx.x;
    if (tid < NE) { lcnt[tid] = 0; limp[tid] = 0.f; }
    __syncthreads();

    int n = blockIdx.x * 256 + tid;
    int e1 = tok_e[2 * n], e2 = tok_e[2 * n + 1];
    float g1 = tok_g[2 * n], g2 = tok_g[2 * n + 1];
    int o1 = atomicAdd(&lcnt[e1], 1);
    int o2 = atomicAdd(&lcnt[e2], 1);
    atomicAdd(&limp[e1], g1);
    atomicAdd(&limp[e2], g2);
    __syncthreads();
    if (tid < NE) {
        lbase[tid] = atomicAdd(&count[tid], lcnt[tid]);
        atomicAdd(&imp[tid], limp[tid]);
    }
    __syncthreads();
    bucket[e1 * N_TOK + lbase[e1] + o1] = 2 * n;
    bucket[e2 * N_TOK + lbase[e2] + o2] = 2 * n + 1;
}

// -------- grouped GEMM, bf16 MFMA 16x16x32, 128x128 tile, BK=32 (m97 layout)
__global__ __launch_bounds__(256) void moe_gemm(
    const u16* __restrict__ xb, const u16* __restrict__ ewt,
    const int* __restrict__ count, const int* __restrict__ bucket,
    u16* __restrict__ y)
{
    int b = blockIdx.x;
    int ft = b & 3;            // feature tile (128 cols)
    int tt = (b >> 2) & 63;    // token tile (128 slots)
    int e  = b >> 8;           // expert
    int cnt = count[e];
    if (tt * 128 >= cnt) return;

    __shared__ int sl[128];
    // union: staging As[128][32] | Bs[128][32] (u16) ; epilogue 4 x (32 x 72)
    __shared__ __align__(16) u16 smem[16384];
    u16* As = smem;
    u16* Bs = smem + 8192;

    int tid = threadIdx.x;
    if (tid < 128) {
        int idx = tt * 128 + tid;
        sl[tid] = (idx < cnt) ? bucket[e * N_TOK + idx] : -1;
    }
    __syncthreads();

    int w = tid >> 6, l = tid & 63;
    int c8 = (l & 3) * 8;
    int r0 = w * 32 + (l >> 2);
    int r1 = r0 + 16;
    int s0 = sl[r0], s1 = sl[r1];
    int ta0 = (s0 < 0) ? 0 : (s0 >> 1);
    int ta1 = (s1 < 0) ? 0 : (s1 >> 1);
    const u16* gA0 = xb + (size_t)ta0 * D + c8;
    const u16* gA1 = xb + (size_t)ta1 * D + c8;
    const u16* gB0 = ewt + ((size_t)e * D + ft * 128 + r0) * D + c8;
    const u16* gB1 = ewt + ((size_t)e * D + ft * 128 + r1) * D + c8;
    u16* lA0 = &As[(w * 32) * 32];
    u16* lA1 = &As[(w * 32 + 16) * 32];
    u16* lB0 = &Bs[(w * 32) * 32];
    u16* lB1 = &Bs[(w * 32 + 16) * 32];

    int wm = w & 1, wn = w >> 1;    // 2x2 waves, each 64x64 out
    int lm = l & 15, quad = l >> 4, kq = quad * 8;

    f32x4 acc[4][4] = {};

    for (int kc = 0; kc < 16; ++kc) {
        __syncthreads();
        gload16(gA0 + kc * 32, lA0);
        gload16(gA1 + kc * 32, lA1);
        gload16(gB0 + kc * 32, lB0);
        gload16(gB1 + kc * 32, lB1);
        __syncthreads();

        bf16x8 af[4], bfv[4];
#pragma unroll
        for (int i = 0; i < 4; ++i)
            af[i] = *(const bf16x8*)&As[(wm * 64 + i * 16 + lm) * 32 + kq];
#pragma unroll
        for (int j = 0; j < 4; ++j)
            bfv[j] = *(const bf16x8*)&Bs[(wn * 64 + j * 16 + lm) * 32 + kq];
#pragma unroll
        for (int i = 0; i < 4; ++i)
#pragma unroll
            for (int j = 0; j < 4; ++j)
                acc[i][j] = __builtin_amdgcn_mfma_f32_16x16x32_bf16(
                    af[i], bfv[j], acc[i][j], 0, 0, 0);
    }

    // ---- epilogue: per-wave LDS transpose, then coalesced 16B stores.
    // C/D layout (m89): col = lane&15, row = quad*4 + reg.
    __syncthreads();                 // all MFMA LDS reads done before overwrite
    u16* Es = smem + w * 2304;       // 32 rows x 72 u16, 16B-aligned rows
#pragma unroll
    for (int h = 0; h < 2; ++h) {
#pragma unroll
        for (int i2 = 0; i2 < 2; ++i2) {
            int i = h * 2 + i2;
#pragma unroll
            for (int j = 0; j < 4; ++j)
#pragma unroll
                for (int r = 0; r < 4; ++r)
                    Es[(i2 * 16 + quad * 4 + r) * 72 + j * 16 + lm] =
                        f2b(acc[i][j][r]);
        }
        int row = l >> 1, hc = l & 1;        // 2 lanes per row, 64B halves
        int s = sl[wm * 64 + h * 32 + row];
        const u16* src = Es + row * 72 + hc * 32;
        u16* dst = y + (size_t)((s < 0) ? 0 : s) * D + ft * 128 + wn * 64 + hc * 32;
        if (s >= 0) {
#pragma unroll
            for (int c = 0; c < 4; ++c)
                *(u16x8*)(dst + c * 8) = *(const u16x8*)(src + c * 8);
        }
    }
}

// -------- combine (blocks 0..4095) | loss (block 4096)
__global__ __launch_bounds__(256) void combine_kernel(
    const u16* __restrict__ y, const float* __restrict__ tok_g,
    const int* __restrict__ count, const float* __restrict__ imp,
    float* __restrict__ out)
{
    if (blockIdx.x == 4096) {
        if (threadIdx.x == 0) {
            float mi = 0.f, ml = 0.f;
            for (int e = 0; e < NE; ++e) { mi += imp[e]; ml += (float)count[e]; }
            mi *= 0.125f; ml *= 0.125f;
            float vi = 0.f, vl = 0.f;
            for (int e = 0; e < NE; ++e) {
                float di = imp[e] - mi;          vi += di * di;
                float dl = (float)count[e] - ml; vl += dl * dl;
            }
            vi *= 0.125f; vl *= 0.125f;
            out[N_TOK * D] = vi / (mi * mi + 1e-10f) + vl / (ml * ml + 1e-10f);
        }
        return;
    }
    int idx = blockIdx.x * 256 + threadIdx.x;
    int n = idx >> 7;
    int c = (idx & 127) * 4;
    const ushort4 ua = *(const ushort4*)(y + (size_t)(2 * n) * D + c);
    const ushort4 ub = *(const ushort4*)(y + (size_t)(2 * n + 1) * D + c);
    float g1 = tok_g[2 * n], g2 = tok_g[2 * n + 1];
    const float eps = 2.2204460492503131e-16f;
    float4 r;
    float v;
    v = g1 * __expf(b2f(ua.x)) + g2 * __expf(b2f(ub.x)); r.x = __logf(v == 0.f ? eps : v);
    v = g1 * __expf(b2f(ua.y)) + g2 * __expf(b2f(ub.y)); r.y = __logf(v == 0.f ? eps : v);
    v = g1 * __expf(b2f(ua.z)) + g2 * __expf(b2f(ub.z)); r.z = __logf(v == 0.f ? eps : v);
    v = g1 * __expf(b2f(ua.w)) + g2 * __expf(b2f(ub.w)); r.w = __logf(v == 0.f ? eps : v);
    *(float4*)(out + (size_t)n * D + c) = r;
}

extern "C" void kernel_launch(void* const* d_in, const int* in_sizes, int n_in,
                              void* d_out, int out_size, void* d_ws, size_t ws_size,
                              hipStream_t stream)
{
    const float* x  = (const float*)d_in[0];
    const float* wg = (const float*)d_in[1];
    const float* ew = (const float*)d_in[2];
    char* ws = (char*)d_ws;
    int*   count  = (int*)(ws + 0);
    float* imp    = (float*)(ws + 64);
    int*   tok_e  = (int*)(ws + OFF_TOKE);
    float* tok_g  = (float*)(ws + OFF_TOKG);
    int*   bucket = (int*)(ws + OFF_BUCK);
    u16*   xb     = (u16*)(ws + OFF_XB);
    u16*   ewt    = (u16*)(ws + OFF_EWT);
    u16*   y      = (u16*)(ws + OFF_Y);
    float* out    = (float*)d_out;

    hipMemsetAsync(ws, 0, 128, stream);   // count + imp (replay-proven path)
    gate_prep_kernel<<<2048 + 512, 256, 0, stream>>>(x, wg, ew, tok_e, tok_g, xb, ewt);
    bucketize_kernel<<<N_TOK / 256, 256, 0, stream>>>(tok_e, tok_g, count, imp, bucket);
    moe_gemm<<<NE * 64 * 4, 256, 0, stream>>>(xb, ewt, count, bucket, y);
    combine_kernel<<<4097, 256, 0, stream>>>(y, tok_g, count, imp, out);
}